// Round 1
// baseline (224.069 us; speedup 1.0000x reference)
//
#include <hip/hip_runtime.h>
#include <hip/hip_bf16.h>
#include <math.h>

typedef __attribute__((ext_vector_type(4))) float f32x4;
typedef __attribute__((ext_vector_type(8))) short short8;
typedef __attribute__((ext_vector_type(4))) short short4v;

__device__ __forceinline__ short f2bf(float f) {
    union { __hip_bfloat16 h; short s; } u;
    u.h = __float2bfloat16(f);
    return u.s;
}

// ---------------- prep: fp32 -> bf16 convert ----------------
__global__ __launch_bounds__(256) void cvt_bf16(const float* __restrict__ in,
                                                short* __restrict__ out, int n) {
    int i = (blockIdx.x * 256 + threadIdx.x) * 8;
    if (i >= n) return;
    float4 a = *reinterpret_cast<const float4*>(in + i);
    float4 b = *reinterpret_cast<const float4*>(in + i + 4);
    short8 o;
    o[0] = f2bf(a.x); o[1] = f2bf(a.y); o[2] = f2bf(a.z); o[3] = f2bf(a.w);
    o[4] = f2bf(b.x); o[5] = f2bf(b.y); o[6] = f2bf(b.z); o[7] = f2bf(b.w);
    *reinterpret_cast<short8*>(out + i) = o;
}

// ---------------- prep: transpose fp32 [K][N] -> bf16 [N][K] ----------------
__global__ __launch_bounds__(256) void transpose_w(const float* __restrict__ W,
                                                   short* __restrict__ Wt,
                                                   int K, int N) {
    __shared__ float tile[64][68];
    const int k0 = blockIdx.x * 64;
    const int n0 = blockIdx.y * 64;
    const int tid = threadIdx.x;
    #pragma unroll
    for (int i = 0; i < 4; ++i) {
        int c = tid + i * 256;          // 0..1023
        int r = c >> 4;                 // 0..63 (k-local)
        int col4 = (c & 15) * 4;        // 0..60 (n-local)
        float4 v = *reinterpret_cast<const float4*>(W + (size_t)(k0 + r) * N + n0 + col4);
        tile[r][col4 + 0] = v.x; tile[r][col4 + 1] = v.y;
        tile[r][col4 + 2] = v.z; tile[r][col4 + 3] = v.w;
    }
    __syncthreads();
    #pragma unroll
    for (int i = 0; i < 4; ++i) {
        int c = tid + i * 256;
        int r2 = c >> 4;                // n-local
        int col4 = (c & 15) * 4;        // k-local
        short4v o;
        #pragma unroll
        for (int j = 0; j < 4; ++j) o[j] = f2bf(tile[col4 + j][r2]);
        *reinterpret_cast<short4v*>(Wt + (size_t)(n0 + r2) * K + k0 + col4) = o;
    }
}

// ---------------- GEMM: C[M,N] = A[M,K](bf16) * Bt[N,K](bf16)^T + bias ----------------
template<bool OUT_BF16>
__global__ __launch_bounds__(256) void gemm_bt(const short* __restrict__ A,
                                               const short* __restrict__ Bt,
                                               const float* __restrict__ bias,
                                               void* __restrict__ C,
                                               int M, int N, int K) {
    constexpr int BM = 128, BN = 128, BK = 64, LDP = BK + 8;
    __shared__ short As[BM * LDP];
    __shared__ short Bs[BN * LDP];
    const int tid = threadIdx.x;
    const int lane = tid & 63, wave = tid >> 6;
    const int bm = blockIdx.x * BM, bn = blockIdx.y * BN;
    const int wr = (wave >> 1) * 64, wc = (wave & 1) * 64;
    const int g = lane >> 4, l15 = lane & 15;

    f32x4 acc[4][4] = {};

    for (int k0 = 0; k0 < K; k0 += BK) {
        __syncthreads();
        #pragma unroll
        for (int i = 0; i < 4; ++i) {
            int c = tid + i * 256;      // 0..1023
            int r = c >> 3;             // 0..127
            int col = (c & 7) * 8;      // 0..56
            *reinterpret_cast<short8*>(&As[r * LDP + col]) =
                *reinterpret_cast<const short8*>(A + (size_t)(bm + r) * K + k0 + col);
            *reinterpret_cast<short8*>(&Bs[r * LDP + col]) =
                *reinterpret_cast<const short8*>(Bt + (size_t)(bn + r) * K + k0 + col);
        }
        __syncthreads();
        #pragma unroll
        for (int kk = 0; kk < 2; ++kk) {
            short8 af[4], bfr[4];
            #pragma unroll
            for (int m = 0; m < 4; ++m)
                af[m] = *reinterpret_cast<const short8*>(&As[(wr + m * 16 + l15) * LDP + kk * 32 + g * 8]);
            #pragma unroll
            for (int n = 0; n < 4; ++n)
                bfr[n] = *reinterpret_cast<const short8*>(&Bs[(wc + n * 16 + l15) * LDP + kk * 32 + g * 8]);
            #pragma unroll
            for (int m = 0; m < 4; ++m)
                #pragma unroll
                for (int n = 0; n < 4; ++n)
                    acc[m][n] = __builtin_amdgcn_mfma_f32_16x16x32_bf16(af[m], bfr[n], acc[m][n], 0, 0, 0);
        }
    }

    #pragma unroll
    for (int m = 0; m < 4; ++m)
        #pragma unroll
        for (int n = 0; n < 4; ++n) {
            int gc = bn + wc + n * 16 + l15;
            float bv = bias[gc];
            #pragma unroll
            for (int r = 0; r < 4; ++r) {
                int gr = bm + wr + m * 16 + g * 4 + r;
                float v = acc[m][n][r] + bv;
                if (OUT_BF16)
                    reinterpret_cast<short*>(C)[(size_t)gr * N + gc] = f2bf(v);
                else
                    reinterpret_cast<float*>(C)[(size_t)gr * N + gc] = v;
            }
        }
}

// ---------------- flash attention ----------------
// kqv: bf16 [B, T, 3C]  (q | k | v, head-interleaved, D=64)
// yatt: bf16 [B, T, C]
__global__ __launch_bounds__(256) void attn_kernel(const short* __restrict__ kqv,
                                                   short* __restrict__ yatt) {
    constexpr int T = 2048, C = 1024, D = 64;
    constexpr int LDK = D + 8;
    __shared__ short Ks[64 * LDK];     // K-tile [kv][d]
    __shared__ short Vt[64 * LDK];     // V-tile transposed [d][kv]
    __shared__ short Ps[4][32 * LDK];  // per-wave P [q][kv]

    const int tid = threadIdx.x;
    const int lane = tid & 63, wave = tid >> 6;
    const int g = lane >> 4, l15 = lane & 15;
    const int qt = blockIdx.x;         // q-tile (128 rows)
    const int h = blockIdx.y;
    const int b = blockIdx.z;
    const int qs = qt * 128;
    const int q0w = qs + wave * 32;    // this wave's first q row

    const size_t rowstride = 3 * C;
    const size_t baseQ = (size_t)b * T * rowstride + (size_t)h * D;
    const size_t baseK = baseQ + C;
    const size_t baseV = baseQ + 2 * C;

    // Q fragments in registers: [m][kk]
    short8 qf[2][2];
    #pragma unroll
    for (int m = 0; m < 2; ++m)
        #pragma unroll
        for (int kk = 0; kk < 2; ++kk)
            qf[m][kk] = *reinterpret_cast<const short8*>(
                kqv + baseQ + (size_t)(q0w + m * 16 + l15) * rowstride + kk * 32 + g * 8);

    f32x4 oacc[2][4] = {};
    float mstate[2][4], lstate[2][4];
    #pragma unroll
    for (int m = 0; m < 2; ++m)
        #pragma unroll
        for (int r = 0; r < 4; ++r) { mstate[m][r] = -INFINITY; lstate[m][r] = 0.f; }

    const int jmax = 2 * qt + 1;
    for (int j = 0; j <= jmax; ++j) {
        const int kvbase = j * 64;
        __syncthreads();
        // stage K [kv][d] and V transposed [d][kv]
        #pragma unroll
        for (int i = 0; i < 2; ++i) {
            int c = tid + i * 256;      // 0..511
            int r = c >> 3;             // kv row 0..63
            int col = (c & 7) * 8;      // d 0..56
            short8 kv8 = *reinterpret_cast<const short8*>(
                kqv + baseK + (size_t)(kvbase + r) * rowstride + col);
            *reinterpret_cast<short8*>(&Ks[r * LDK + col]) = kv8;
            short8 vv8 = *reinterpret_cast<const short8*>(
                kqv + baseV + (size_t)(kvbase + r) * rowstride + col);
            #pragma unroll
            for (int jj = 0; jj < 8; ++jj) Vt[(col + jj) * LDK + r] = vv8[jj];
        }
        __syncthreads();

        // S = Q K^T * scale, causal mask
        f32x4 sacc[2][4] = {};
        #pragma unroll
        for (int kk = 0; kk < 2; ++kk) {
            short8 bfr[4];
            #pragma unroll
            for (int n = 0; n < 4; ++n)
                bfr[n] = *reinterpret_cast<const short8*>(&Ks[(n * 16 + l15) * LDK + kk * 32 + g * 8]);
            #pragma unroll
            for (int m = 0; m < 2; ++m)
                #pragma unroll
                for (int n = 0; n < 4; ++n)
                    sacc[m][n] = __builtin_amdgcn_mfma_f32_16x16x32_bf16(qf[m][kk], bfr[n], sacc[m][n], 0, 0, 0);
        }
        #pragma unroll
        for (int m = 0; m < 2; ++m)
            #pragma unroll
            for (int n = 0; n < 4; ++n) {
                f32x4 v = sacc[m][n];
                #pragma unroll
                for (int r = 0; r < 4; ++r) {
                    int row = q0w + m * 16 + g * 4 + r;
                    int col = kvbase + n * 16 + l15;
                    float s = v[r] * 0.125f;
                    v[r] = (col <= row) ? s : -INFINITY;
                }
                sacc[m][n] = v;
            }

        // online softmax + write P (bf16) to wave-private LDS
        #pragma unroll
        for (int m = 0; m < 2; ++m)
            #pragma unroll
            for (int r = 0; r < 4; ++r) {
                float rm = fmaxf(fmaxf(sacc[m][0][r], sacc[m][1][r]),
                                 fmaxf(sacc[m][2][r], sacc[m][3][r]));
                #pragma unroll
                for (int w = 1; w < 16; w <<= 1) rm = fmaxf(rm, __shfl_xor(rm, w));
                float mn = fmaxf(mstate[m][r], rm);
                float corr = __expf(mstate[m][r] - mn);
                mstate[m][r] = mn;
                float ls = 0.f;
                #pragma unroll
                for (int n = 0; n < 4; ++n) {
                    float p = __expf(sacc[m][n][r] - mn);
                    ls += p;
                    Ps[wave][(m * 16 + g * 4 + r) * LDK + n * 16 + l15] = f2bf(p);
                }
                #pragma unroll
                for (int w = 1; w < 16; w <<= 1) ls += __shfl_xor(ls, w);
                lstate[m][r] = lstate[m][r] * corr + ls;
                #pragma unroll
                for (int nd = 0; nd < 4; ++nd) oacc[m][nd][r] *= corr;
            }
        __syncthreads();

        // O += P V
        #pragma unroll
        for (int kk = 0; kk < 2; ++kk) {
            short8 vb[4];
            #pragma unroll
            for (int nd = 0; nd < 4; ++nd)
                vb[nd] = *reinterpret_cast<const short8*>(&Vt[(nd * 16 + l15) * LDK + kk * 32 + g * 8]);
            #pragma unroll
            for (int m = 0; m < 2; ++m) {
                short8 pa = *reinterpret_cast<const short8*>(&Ps[wave][(m * 16 + l15) * LDK + kk * 32 + g * 8]);
                #pragma unroll
                for (int nd = 0; nd < 4; ++nd)
                    oacc[m][nd] = __builtin_amdgcn_mfma_f32_16x16x32_bf16(pa, vb[nd], oacc[m][nd], 0, 0, 0);
            }
        }
    }

    // epilogue: O / l -> yatt
    #pragma unroll
    for (int m = 0; m < 2; ++m)
        #pragma unroll
        for (int nd = 0; nd < 4; ++nd)
            #pragma unroll
            for (int r = 0; r < 4; ++r) {
                int row = q0w + m * 16 + g * 4 + r;
                int col = nd * 16 + l15;
                float o = oacc[m][nd][r] / lstate[m][r];
                yatt[(size_t)b * T * C + (size_t)row * C + h * D + col] = f2bf(o);
            }
}

// ---------------- launch ----------------
extern "C" void kernel_launch(void* const* d_in, const int* in_sizes, int n_in,
                              void* d_out, int out_size, void* d_ws, size_t ws_size,
                              hipStream_t stream) {
    constexpr int B = 2, T = 2048, C = 1024, H = 16;
    constexpr int M = B * T;       // 4096
    constexpr int N1 = 3 * C;      // 3072
    constexpr int K = C;           // 1024

    const float* x      = (const float*)d_in[0];
    const float* W_attn = (const float*)d_in[1];
    const float* b_attn = (const float*)d_in[2];
    const float* W_proj = (const float*)d_in[3];
    const float* b_proj = (const float*)d_in[4];
    float* out = (float*)d_out;

    char* ws = (char*)d_ws;
    short* x_bf    = (short*)(ws);                          // M*K*2      = 8388608
    short* Wt_attn = (short*)(ws + 8388608);                // N1*K*2     = 6291456
    short* Wt_proj = (short*)(ws + 14680064);               // C*K*2      = 2097152
    short* kqv     = (short*)(ws + 16777216);               // M*N1*2     = 25165824
    short* yatt    = (short*)(ws + 41943040);               // M*C*2      = 8388608

    cvt_bf16<<<dim3(M * K / (256 * 8)), 256, 0, stream>>>(x, x_bf, M * K);
    transpose_w<<<dim3(K / 64, N1 / 64), 256, 0, stream>>>(W_attn, Wt_attn, K, N1);
    transpose_w<<<dim3(K / 64, C / 64), 256, 0, stream>>>(W_proj, Wt_proj, K, C);

    gemm_bt<true><<<dim3(M / 128, N1 / 128), 256, 0, stream>>>(x_bf, Wt_attn, b_attn, kqv, M, N1, K);
    attn_kernel<<<dim3(T / 128, H, B), 256, 0, stream>>>(kqv, yatt);
    gemm_bt<false><<<dim3(M / 128, C / 128), 256, 0, stream>>>(yatt, Wt_proj, b_proj, out, M, C, C);
}

// Round 2
// 181.599 us; speedup vs baseline: 1.2339x; 1.2339x over previous
//
#include <hip/hip_runtime.h>
#include <hip/hip_bf16.h>
#include <math.h>

typedef __attribute__((ext_vector_type(4))) float f32x4;
typedef __attribute__((ext_vector_type(8))) short short8;
typedef __attribute__((ext_vector_type(4))) short short4v;

__device__ __forceinline__ short f2bf(float f) {
    union { __hip_bfloat16 h; short s; } u;
    u.h = __float2bfloat16(f);
    return u.s;
}

// ---------------- prep: fp32 -> bf16 convert ----------------
__global__ __launch_bounds__(256) void cvt_bf16(const float* __restrict__ in,
                                                short* __restrict__ out, int n) {
    int i = (blockIdx.x * 256 + threadIdx.x) * 8;
    if (i >= n) return;
    float4 a = *reinterpret_cast<const float4*>(in + i);
    float4 b = *reinterpret_cast<const float4*>(in + i + 4);
    short8 o;
    o[0] = f2bf(a.x); o[1] = f2bf(a.y); o[2] = f2bf(a.z); o[3] = f2bf(a.w);
    o[4] = f2bf(b.x); o[5] = f2bf(b.y); o[6] = f2bf(b.z); o[7] = f2bf(b.w);
    *reinterpret_cast<short8*>(out + i) = o;
}

// ---------------- prep: transpose fp32 [K][N] -> bf16 [N][K] ----------------
__global__ __launch_bounds__(256) void transpose_w(const float* __restrict__ W,
                                                   short* __restrict__ Wt,
                                                   int K, int N) {
    __shared__ float tile[64][68];
    const int k0 = blockIdx.x * 64;
    const int n0 = blockIdx.y * 64;
    const int tid = threadIdx.x;
    #pragma unroll
    for (int i = 0; i < 4; ++i) {
        int c = tid + i * 256;
        int r = c >> 4;
        int col4 = (c & 15) * 4;
        float4 v = *reinterpret_cast<const float4*>(W + (size_t)(k0 + r) * N + n0 + col4);
        tile[r][col4 + 0] = v.x; tile[r][col4 + 1] = v.y;
        tile[r][col4 + 2] = v.z; tile[r][col4 + 3] = v.w;
    }
    __syncthreads();
    #pragma unroll
    for (int i = 0; i < 4; ++i) {
        int c = tid + i * 256;
        int r2 = c >> 4;
        int col4 = (c & 15) * 4;
        short4v o;
        #pragma unroll
        for (int j = 0; j < 4; ++j) o[j] = f2bf(tile[col4 + j][r2]);
        *reinterpret_cast<short4v*>(Wt + (size_t)(n0 + r2) * K + k0 + col4) = o;
    }
}

// ---------------- GEMM: C[M,N] = A[M,K](bf16) * Bt[N,K](bf16)^T + bias ----------------
// MODE 0: C = float out.
// MODE 1: split epilogue for kqv: cols <2048 -> bf16 qk buffer [M][2048]
//         (q cols additionally scaled by 0.125 = 1/sqrt(D)); cols >=2048 ->
//         transposed V buffer vt [B*H*D][T] bf16.
template<int MODE>
__global__ __launch_bounds__(256) void gemm_bt(const short* __restrict__ A,
                                               const short* __restrict__ Bt,
                                               const float* __restrict__ bias,
                                               void* __restrict__ C,
                                               short* __restrict__ vt,
                                               int M, int N, int K) {
    constexpr int BM = 128, BN = 128, BK = 64, LDP = BK + 8;
    __shared__ short As[BM * LDP];
    __shared__ short Bs[BN * LDP];
    const int tid = threadIdx.x;
    const int lane = tid & 63, wave = tid >> 6;
    const int bm = blockIdx.x * BM, bn = blockIdx.y * BN;
    const int wr = (wave >> 1) * 64, wc = (wave & 1) * 64;
    const int g = lane >> 4, l15 = lane & 15;

    f32x4 acc[4][4] = {};

    for (int k0 = 0; k0 < K; k0 += BK) {
        __syncthreads();
        #pragma unroll
        for (int i = 0; i < 4; ++i) {
            int c = tid + i * 256;
            int r = c >> 3;
            int col = (c & 7) * 8;
            *reinterpret_cast<short8*>(&As[r * LDP + col]) =
                *reinterpret_cast<const short8*>(A + (size_t)(bm + r) * K + k0 + col);
            *reinterpret_cast<short8*>(&Bs[r * LDP + col]) =
                *reinterpret_cast<const short8*>(Bt + (size_t)(bn + r) * K + k0 + col);
        }
        __syncthreads();
        #pragma unroll
        for (int kk = 0; kk < 2; ++kk) {
            short8 af[4], bfr[4];
            #pragma unroll
            for (int m = 0; m < 4; ++m)
                af[m] = *reinterpret_cast<const short8*>(&As[(wr + m * 16 + l15) * LDP + kk * 32 + g * 8]);
            #pragma unroll
            for (int n = 0; n < 4; ++n)
                bfr[n] = *reinterpret_cast<const short8*>(&Bs[(wc + n * 16 + l15) * LDP + kk * 32 + g * 8]);
            #pragma unroll
            for (int m = 0; m < 4; ++m)
                #pragma unroll
                for (int n = 0; n < 4; ++n)
                    acc[m][n] = __builtin_amdgcn_mfma_f32_16x16x32_bf16(af[m], bfr[n], acc[m][n], 0, 0, 0);
        }
    }

    #pragma unroll
    for (int m = 0; m < 4; ++m)
        #pragma unroll
        for (int n = 0; n < 4; ++n) {
            int gc = bn + wc + n * 16 + l15;
            float bv = bias[gc];
            int gr0 = bm + wr + m * 16 + g * 4;
            if (MODE == 0) {
                #pragma unroll
                for (int r = 0; r < 4; ++r)
                    reinterpret_cast<float*>(C)[(size_t)(gr0 + r) * N + gc] = acc[m][n][r] + bv;
            } else {
                if (gc < 2048) {
                    float sc = (gc < 1024) ? 0.125f : 1.0f;
                    short* qkp = reinterpret_cast<short*>(C);
                    #pragma unroll
                    for (int r = 0; r < 4; ++r)
                        qkp[(size_t)(gr0 + r) * 2048 + gc] = f2bf((acc[m][n][r] + bv) * sc);
                } else {
                    int cv = gc - 2048;            // h*64 + d
                    int bb = gr0 >> 11;            // batch
                    int t0 = gr0 & 2047;           // time (multiple of 4)
                    short4v o;
                    #pragma unroll
                    for (int r = 0; r < 4; ++r) o[r] = f2bf(acc[m][n][r] + bv);
                    *reinterpret_cast<short4v*>(&vt[((size_t)(bb << 10) + cv) * 2048 + t0]) = o;
                }
            }
        }
}

// ---------------- flash attention ----------------
// qk: bf16 [B, T, 2048]  (q*0.125 | k), head-interleaved, D=64
// vt: bf16 [B*H*D, T]    (V pre-transposed)
// yatt: bf16 [B, T, C]
__global__ __launch_bounds__(256) void attn_kernel(const short* __restrict__ qk,
                                                   const short* __restrict__ vt,
                                                   short* __restrict__ yatt) {
    constexpr int T = 2048;
    constexpr int LDK = 72;            // 64 + 8 pad (keeps rows 16B-aligned, 2-way banks)
    __shared__ short Ks[64 * LDK];     // K-tile [kv][d]
    __shared__ short Vs[64 * LDK];     // V-tile [d][kv] (already transposed in global)
    __shared__ short Ps[4][16 * LDK];  // per-wave P [q][kv]

    const int tid = threadIdx.x;
    const int lane = tid & 63, wave = tid >> 6;
    const int g = lane >> 4, l15 = lane & 15;

    // block decode: XCD-grouped (same (b,h) stays in one XCD L2) with
    // complementary-qt pairing so each CU's resident blocks sum to equal work.
    const int i = blockIdx.x;          // 0..1023
    const int x = i & 7;               // XCD slot
    const int u = i >> 3;              // 0..127
    const int g2 = u >> 5;             // 0..3  (group-within-XCD)
    const int v = u & 31;
    const int qt = (g2 & 1) ? v : 31 - v;   // pair heavy with light
    const int grp = x * 4 + g2;        // 0..31
    const int h = grp & 15, b = grp >> 4;

    const int qs = qt * 64;
    const int q0w = qs + wave * 16;    // this wave's first q row

    const size_t baseQ = (size_t)b * T * 2048 + (size_t)h * 64;
    const size_t baseK = baseQ + 1024;
    const size_t vbase = ((size_t)b * 1024 + (size_t)h * 64) * 2048;

    // Q fragments in registers (already scaled by 1/8)
    short8 qf[2];
    #pragma unroll
    for (int kk = 0; kk < 2; ++kk)
        qf[kk] = *reinterpret_cast<const short8*>(
            qk + baseQ + (size_t)(q0w + l15) * 2048 + kk * 32 + g * 8);

    f32x4 oacc[4] = {};
    float mst[4], lst[4];
    #pragma unroll
    for (int r = 0; r < 4; ++r) { mst[r] = -INFINITY; lst[r] = 0.f; }

    for (int j = 0; j <= qt; ++j) {
        const int kb = j * 64;
        __syncthreads();               // all waves done reading Ks/Vs of prev iter
        #pragma unroll
        for (int it = 0; it < 2; ++it) {
            int c = tid + it * 256;    // 0..511
            int r = c >> 3;            // 0..63
            int col = (c & 7) * 8;     // 0..56
            *reinterpret_cast<short8*>(&Ks[r * LDK + col]) =
                *reinterpret_cast<const short8*>(qk + baseK + (size_t)(kb + r) * 2048 + col);
            *reinterpret_cast<short8*>(&Vs[r * LDK + col]) =
                *reinterpret_cast<const short8*>(vt + vbase + (size_t)r * 2048 + kb + col);
        }
        __syncthreads();

        const bool diag = (j == qt);
        const int nmax = diag ? (wave | 1) : 3;

        // S = (Q/8) K^T
        f32x4 sacc[4] = {};
        __builtin_amdgcn_s_setprio(1);
        #pragma unroll
        for (int kk = 0; kk < 2; ++kk) {
            #pragma unroll
            for (int n = 0; n < 4; ++n) {
                if (n > nmax) break;
                short8 bfr = *reinterpret_cast<const short8*>(&Ks[(n * 16 + l15) * LDK + kk * 32 + g * 8]);
                sacc[n] = __builtin_amdgcn_mfma_f32_16x16x32_bf16(qf[kk], bfr, sacc[n], 0, 0, 0);
            }
        }
        __builtin_amdgcn_s_setprio(0);

        if (diag) {
            #pragma unroll
            for (int n = 0; n < 4; ++n) {
                if (n > nmax) break;
                #pragma unroll
                for (int r = 0; r < 4; ++r) {
                    int row = q0w + g * 4 + r;
                    int col = kb + n * 16 + l15;
                    if (col > row) sacc[n][r] = -INFINITY;
                }
            }
        }

        // online softmax (rows live in one 16-lane group; Ps is wave-private)
        #pragma unroll
        for (int r = 0; r < 4; ++r) {
            float rm = sacc[0][r];
            #pragma unroll
            for (int n = 1; n < 4; ++n) {
                if (n > nmax) break;
                rm = fmaxf(rm, sacc[n][r]);
            }
            #pragma unroll
            for (int w = 1; w < 16; w <<= 1) rm = fmaxf(rm, __shfl_xor(rm, w));
            float mn = fmaxf(mst[r], rm);
            float corr = __expf(mst[r] - mn);
            mst[r] = mn;
            float ls = 0.f;
            #pragma unroll
            for (int n = 0; n < 4; ++n) {
                if (n > nmax) break;
                float p = __expf(sacc[n][r] - mn);
                ls += p;
                Ps[wave][(g * 4 + r) * LDK + n * 16 + l15] = f2bf(p);
            }
            #pragma unroll
            for (int w = 1; w < 16; w <<= 1) ls += __shfl_xor(ls, w);
            lst[r] = lst[r] * corr + ls;
            #pragma unroll
            for (int nd = 0; nd < 4; ++nd) oacc[nd][r] *= corr;
        }

        // O += P V   (no barrier needed: Ps wave-private, Vs unchanged)
        const int kkmax = diag ? (wave >> 1) : 1;
        __builtin_amdgcn_s_setprio(1);
        #pragma unroll
        for (int kk = 0; kk < 2; ++kk) {
            if (kk > kkmax) break;
            short8 pa = *reinterpret_cast<const short8*>(&Ps[wave][l15 * LDK + kk * 32 + g * 8]);
            #pragma unroll
            for (int nd = 0; nd < 4; ++nd) {
                short8 vb = *reinterpret_cast<const short8*>(&Vs[(nd * 16 + l15) * LDK + kk * 32 + g * 8]);
                oacc[nd] = __builtin_amdgcn_mfma_f32_16x16x32_bf16(pa, vb, oacc[nd], 0, 0, 0);
            }
        }
        __builtin_amdgcn_s_setprio(0);
    }

    #pragma unroll
    for (int r = 0; r < 4; ++r) {
        float rl = 1.0f / lst[r];
        int row = q0w + g * 4 + r;
        #pragma unroll
        for (int nd = 0; nd < 4; ++nd) {
            int col = nd * 16 + l15;
            yatt[((size_t)b * T + row) * 1024 + h * 64 + col] = f2bf(oacc[nd][r] * rl);
        }
    }
}

// ---------------- launch ----------------
extern "C" void kernel_launch(void* const* d_in, const int* in_sizes, int n_in,
                              void* d_out, int out_size, void* d_ws, size_t ws_size,
                              hipStream_t stream) {
    constexpr int B = 2, T = 2048, C = 1024;
    constexpr int M = B * T;       // 4096
    constexpr int N1 = 3 * C;      // 3072
    constexpr int K = C;           // 1024

    const float* x      = (const float*)d_in[0];
    const float* W_attn = (const float*)d_in[1];
    const float* b_attn = (const float*)d_in[2];
    const float* W_proj = (const float*)d_in[3];
    const float* b_proj = (const float*)d_in[4];
    float* out = (float*)d_out;

    char* ws = (char*)d_ws;
    short* x_bf    = (short*)(ws);                          // M*K*2        = 8388608
    short* Wt_attn = (short*)(ws + 8388608);                // N1*K*2       = 6291456
    short* Wt_proj = (short*)(ws + 14680064);               // C*K*2        = 2097152
    short* qk      = (short*)(ws + 16777216);               // M*2048*2     = 16777216
    short* vt      = (short*)(ws + 33554432);               // B*1024*T*2   = 8388608
    short* yatt    = (short*)(ws + 41943040);               // M*C*2        = 8388608

    cvt_bf16<<<dim3(M * K / (256 * 8)), 256, 0, stream>>>(x, x_bf, M * K);
    transpose_w<<<dim3(K / 64, N1 / 64), 256, 0, stream>>>(W_attn, Wt_attn, K, N1);
    transpose_w<<<dim3(K / 64, C / 64), 256, 0, stream>>>(W_proj, Wt_proj, K, C);

    gemm_bt<1><<<dim3(M / 128, N1 / 128), 256, 0, stream>>>(x_bf, Wt_attn, b_attn, qk, vt, M, N1, K);
    attn_kernel<<<dim3(1024), 256, 0, stream>>>(qk, vt, yatt);
    gemm_bt<0><<<dim3(M / 128, C / 128), 256, 0, stream>>>(yatt, Wt_proj, b_proj, out, nullptr, M, C, C);
}